// Round 15
// baseline (206.861 us; speedup 1.0000x reference)
//
#include <hip/hip_runtime.h>

// Problem constants (B, N, K, P, D, F, H) = (8, 20, 2, 320, 3, 64, 64)
constexpr int B_ = 8, N_ = 20, K_ = 2, P_ = 320, D_ = 3, F_ = 64, H_ = 64;
constexpr int Q_ = K_ * P_;          // 640 rows = flattened (K,P)
constexpr float EPS_ = 1e-8f;
constexpr float LOG2E_ = 1.4426950408889634f;
constexpr int CT_ = 8;               // tiles per (b,n)
constexpr int CR_ = 80;              // rows per tile; tile>=4 -> k=1 (uniform)

// ws layout (float units)
constexpr size_t WV_OFF   = 0;                    // 160*640 unnormalized wvals
constexpr size_t PART_OFF = (size_t)160 * Q_;     // 1280 tile partials
constexpr size_t CNT_OFF  = PART_OFF + 1280;      // 160 int counters

// Last-block-done fusion (replay-safe, unlike R12's flags): counters are
// re-zeroed by a tiny kernel INSIDE this launch, so graph replays are clean.
// Pattern = CUDA threadFenceReduction: stores; threadfence; syncthreads;
// tid0 atomicAdd(acq_rel, agent); last block acquires, sums 8 partials,
// writes normalized out ONCE. Coop round (R14) proved this exact 8x80
// geometry's accuracy; grid.sync was the only bad part (~80us on this stack).
// NO inline asm (R3-R8 curse).
__global__ void zero_counters(int* __restrict__ cnt)
{
    const int i = threadIdx.x;
    if (i < B_ * N_) cnt[i] = 0;
}

__global__ __launch_bounds__(256) void main_kernel(
    const float* __restrict__ X,      // (B,N,K,P,D)
    const float* __restrict__ W,      // (B,N,K,P)
    const float* __restrict__ feats,  // (B,N,F)
    const float* __restrict__ mu,     // (N,K,D)
    const float* __restrict__ W1,     // (N,F,H)
    const float* __restrict__ Wx,     // (N,D,H)
    const float* __restrict__ b1,     // (N,H)
    const float* __restrict__ W2,     // (N,H)
    const float* __restrict__ bias2,  // (N,)
    const int* __restrict__ nbr,      // (N,2)
    float* __restrict__ wsWv,         // (160*640,) unnormalized wvals
    float* __restrict__ wsPart,       // (1280,) tile partials
    int*   __restrict__ wsCnt,        // (160,) arrival counters (pre-zeroed)
    float* __restrict__ out)          // (B,N,K,P)
{
    __shared__ float4 sQ[Q_];            // neighbor point q: (x, y, z, c)
    __shared__ float4 aT[CR_];           // row: (4L*a0, 4L*a1, 4L*a2, -2L*|a|^2)
    __shared__ float4 xT[CR_];           // row: (x0, x1, x2, 0)
    __shared__ float4 gT[H_];            // h: (wx0, wx1, wx2, w2)
    __shared__ float  hbT[H_];           // h: hf + b1
    __shared__ float  gpart[H_][5];      // gemv f-segment partials (4 used)
    __shared__ float  tgate[CR_][5];     // gate h-segment partials (4 used)
    __shared__ float  part[CR_][17];     // row x slice partials (16 used)
    __shared__ float  red[4];
    __shared__ float  invW;              // 1/(sum W_neighbor + EPS)
    __shared__ int    isLast;

    const int blk  = blockIdx.x;         // 0..1279
    const int bn   = blk >> 3;
    const int tile = blk & 7;
    const int b    = bn / N_;
    const int n    = bn - b * N_;
    const int tid  = threadIdx.x;        // 0..255
    const int wave = tid >> 6;
    const int lane = tid & 63;
    const int k    = (tile >= 4) ? 1 : 0;
    const int r0   = tile * CR_;         // row base in (k*320+p) flattening
    const int j    = nbr[n * 2 + k];     // component k pairs with neighbor k

    // ---- stage neighbor j's 640 points (vectorized: 4 points per thread) ----
    const size_t nbase = ((size_t)b * N_ + j) * Q_;
    float wsum = 0.f;
    if (tid < Q_ / 4) {                  // threads 0..159
        const int t = tid;
        const float4* xv = (const float4*)(X + nbase * D_);   // 16B-aligned
        const float4 f0 = xv[3 * t];
        const float4 f1 = xv[3 * t + 1];
        const float4 f2 = xv[3 * t + 2];
        const float4 w4 = ((const float4*)(W + nbase))[t];    // 16B-aligned
        const float c0 = w4.x * __builtin_amdgcn_exp2f(-2.f * LOG2E_ *
                         (f0.x * f0.x + f0.y * f0.y + f0.z * f0.z));
        const float c1 = w4.y * __builtin_amdgcn_exp2f(-2.f * LOG2E_ *
                         (f0.w * f0.w + f1.x * f1.x + f1.y * f1.y));
        const float c2 = w4.z * __builtin_amdgcn_exp2f(-2.f * LOG2E_ *
                         (f1.z * f1.z + f1.w * f1.w + f2.x * f2.x));
        const float c3 = w4.w * __builtin_amdgcn_exp2f(-2.f * LOG2E_ *
                         (f2.y * f2.y + f2.z * f2.z + f2.w * f2.w));
        sQ[4 * t]     = make_float4(f0.x, f0.y, f0.z, c0);
        sQ[4 * t + 1] = make_float4(f0.w, f1.x, f1.y, c1);
        sQ[4 * t + 2] = make_float4(f1.z, f1.w, f2.x, c2);
        sQ[4 * t + 3] = make_float4(f2.y, f2.z, f2.w, c3);
        wsum = (w4.x + w4.y) + (w4.z + w4.w);
    }
    {   // block-reduce neighbor weight sum (zeros from tid>=160)
        float v = wsum;
        #pragma unroll
        for (int off = 32; off > 0; off >>= 1) v += __shfl_down(v, off, 64);
        if (lane == 0) red[wave] = v;
    }

    // ---- hb gemv, parallel over 256 threads: h = tid&63, f-seg = tid>>6 ----
    {
        const int h = tid & 63, seg = tid >> 6;
        const float* fp  = feats + (size_t)bn * F_;
        const float* w1p = W1 + (size_t)n * F_ * H_ + h;
        float acc = 0.f;
        #pragma unroll
        for (int f = 0; f < 16; ++f) {
            const int ff = seg * 16 + f;
            acc = fmaf(fp[ff], w1p[(size_t)ff * H_], acc);
        }
        gpart[h][seg] = acc;
    }

    // ---- per-row params (threads 0..79) + gate tables (threads 0..63) ----
    if (tid < CR_) {
        const int gr = r0 + tid;         // flattened row of this (b,n)
        const float* xp = X + ((size_t)bn * Q_ + gr) * D_;
        const float x0 = xp[0], x1 = xp[1], x2 = xp[2];
        const float* mup = mu + (n * K_ + k) * D_;
        const float a0 = x0 - mup[0];
        const float a1 = x1 - mup[1];
        const float a2 = x2 - mup[2];
        const float ra2 = a0 * a0 + a1 * a1 + a2 * a2;
        aT[tid] = make_float4(a0 * (4.f * LOG2E_), a1 * (4.f * LOG2E_),
                              a2 * (4.f * LOG2E_), -2.f * LOG2E_ * ra2);
        xT[tid] = make_float4(x0, x1, x2, 0.f);
    }
    if (tid < H_) {
        const float* wxp = Wx + (size_t)n * D_ * H_ + tid;
        gT[tid] = make_float4(wxp[0], wxp[H_], wxp[2 * H_], W2[n * H_ + tid]);
    }
    __syncthreads();

    if (tid < H_)
        hbT[tid] = ((gpart[tid][0] + gpart[tid][1]) +
                    (gpart[tid][2] + gpart[tid][3])) + b1[n * H_ + tid];
    if (tid == 0)
        invW = 1.f / (((red[0] + red[1]) + (red[2] + red[3])) + EPS_);

    // ---- q-pass: thread = (row-group g: 5 rows, slice s: 40 strided q) ----
    const int g = tid >> 4;              // 0..15 (rows 5g..5g+4 of the tile)
    const int s = tid & 15;              // 0..15
    float S0[5], S1[5], S2[5], RA[5], acc[5];
    #pragma unroll
    for (int jj = 0; jj < 5; ++jj) {
        const float4 av = aT[g * 5 + jj];
        S0[jj] = av.x; S1[jj] = av.y; S2[jj] = av.z; RA[jj] = av.w;
        acc[jj] = 0.f;
    }
    #pragma unroll 4
    for (int i = 0; i < Q_ / 16; ++i) {  // 40 q per thread
        const float4 Pq = sQ[i * 16 + s];
        #pragma unroll
        for (int jj = 0; jj < 5; ++jj) {
            const float d = fmaf(Pq.x, S0[jj],
                            fmaf(Pq.y, S1[jj],
                            fmaf(Pq.z, S2[jj], RA[jj])));
            acc[jj] = fmaf(Pq.w, __builtin_amdgcn_exp2f(d), acc[jj]);
        }
    }
    #pragma unroll
    for (int jj = 0; jj < 5; ++jj)
        part[g * 5 + jj][s] = acc[jj];

    __syncthreads();

    // ---- gate phase A: rows 0..63 by all threads, rows 64..79 by tid<64 ----
    {
        const int row = tid & 63, seg = tid >> 6;
        const float4 xr = xT[row];
        float accg = 0.f;
        #pragma unroll
        for (int hh = 0; hh < 16; ++hh) {
            const int h = seg * 16 + hh;
            const float4 gv = gT[h];
            float t = fmaf(xr.x, gv.x, fmaf(xr.y, gv.y, fmaf(xr.z, gv.z, hbT[h])));
            t = fmaxf(t, 0.f);
            accg = fmaf(t, gv.w, accg);
        }
        tgate[row][seg] = accg;
    }
    if (tid < 64) {
        const int row = 64 + (tid & 15), seg = tid >> 4;
        const float4 xr = xT[row];
        float accg = 0.f;
        #pragma unroll
        for (int hh = 0; hh < 16; ++hh) {
            const int h = seg * 16 + hh;
            const float4 gv = gT[h];
            float t = fmaf(xr.x, gv.x, fmaf(xr.y, gv.y, fmaf(xr.z, gv.z, hbT[h])));
            t = fmaxf(t, 0.f);
            accg = fmaf(t, gv.w, accg);
        }
        tgate[row][seg] = accg;
    }
    __syncthreads();

    // ---- phase B: threads 0..79 compute wval -> ws (unnormalized) ----
    float wval = 0.f;
    if (tid < CR_) {
        const int row = tid;
        const float* pr = part[row];
        const float msg =
            (((pr[0] + pr[1]) + (pr[2] + pr[3])) + ((pr[4] + pr[5]) + (pr[6] + pr[7]))) +
            (((pr[8] + pr[9]) + (pr[10] + pr[11])) + ((pr[12] + pr[13]) + (pr[14] + pr[15])));
        const float accg = bias2[n] + ((tgate[row][0] + tgate[row][1]) +
                                       (tgate[row][2] + tgate[row][3]));
        const float u = 1.f / (1.f + __expf(-accg));
        wval = u * msg * invW;           // invW: exact linear factor
        wsWv[(size_t)bn * Q_ + r0 + row] = wval;
    }
    // block-reduce wval over threads 0..79 (others contribute 0)
    {
        float v = wval;
        #pragma unroll
        for (int off = 32; off > 0; off >>= 1) v += __shfl_down(v, off, 64);
        if (lane == 0) red[wave] = v;
        __syncthreads();
        if (tid == 0)
            wsPart[blk] = (red[0] + red[1]) + (red[2] + red[3]);
    }

    // ---- arrival: release stores, count; last block normalizes ----
    __threadfence();                     // release this block's ws stores
    __syncthreads();
    if (tid == 0) {
        const int old = __hip_atomic_fetch_add(&wsCnt[bn], 1, __ATOMIC_ACQ_REL,
                                               __HIP_MEMORY_SCOPE_AGENT);
        isLast = (old == CT_ - 1);
    }
    __syncthreads();
    if (!isLast) return;
    __threadfence();                     // acquire siblings' ws stores

    const float* p = wsPart + bn * CT_;
    const float ssum = ((p[0] + p[1]) + (p[2] + p[3])) +
                       ((p[4] + p[5]) + (p[6] + p[7]));
    const float inv = 1.f / (ssum + EPS_);
    const float* wv = wsWv + (size_t)bn * Q_;
    float* ob = out + (size_t)bn * Q_;
    for (int r = tid; r < Q_; r += 256)
        ob[r] = wv[r] * inv;             // out written once, normalized
}

extern "C" void kernel_launch(void* const* d_in, const int* in_sizes, int n_in,
                              void* d_out, int out_size, void* d_ws, size_t ws_size,
                              hipStream_t stream) {
    const float* X     = (const float*)d_in[0];
    const float* W     = (const float*)d_in[1];
    const float* feats = (const float*)d_in[2];
    const float* mu    = (const float*)d_in[3];
    const float* W1    = (const float*)d_in[4];
    const float* Wx    = (const float*)d_in[5];
    const float* b1    = (const float*)d_in[6];
    const float* W2    = (const float*)d_in[7];
    const float* bias2 = (const float*)d_in[8];
    const int*   nbr   = (const int*)d_in[9];
    float*       out   = (float*)d_out;

    float* wsf    = (float*)d_ws;
    float* wsWv   = wsf + WV_OFF;
    float* wsPart = wsf + PART_OFF;
    int*   wsCnt  = (int*)(wsf + CNT_OFF);

    zero_counters<<<1, 256, 0, stream>>>(wsCnt);
    main_kernel<<<B_ * N_ * CT_, 256, 0, stream>>>(
        X, W, feats, mu, W1, Wx, b1, W2, bias2, nbr, wsWv, wsPart, wsCnt, out);
}

// Round 16
// 88.989 us; speedup vs baseline: 2.3246x; 2.3246x over previous
//
#include <hip/hip_runtime.h>

// Problem constants (B, N, K, P, D, F, H) = (8, 20, 2, 320, 3, 64, 64)
constexpr int B_ = 8, N_ = 20, K_ = 2, P_ = 320, D_ = 3, F_ = 64, H_ = 64;
constexpr int Q_ = K_ * P_;          // 640 rows = flattened (K,P)
constexpr float EPS_ = 1e-8f;
constexpr float LOG2E_ = 1.4426950408889634f;
constexpr int CT_ = 8;               // tiles per (b,n)
constexpr int CR_ = 80;              // rows per tile; tile>=4 -> k=1 (uniform)

// Two-kernel structure (R13-proven tail: plain stores, no fences/atomics).
// All single-launch fusions are empirically closed on this stack:
//   R12 flags: harness replays without re-zeroing out -> not replay-safe.
//   R14 grid.sync: ~80us at 1280 blocks.
//   R15 threadfence+atomic counter: L2 writeback/invalidate per block -> 160us.
// This round: the R14/R15 accuracy-proven 8x80 geometry (1280 blocks, 20% less
// aggregate staging than 10x64) with the R13 tail. NO inline asm (R3-R8 curse).
__global__ __launch_bounds__(256) void main_kernel(
    const float* __restrict__ X,      // (B,N,K,P,D)
    const float* __restrict__ W,      // (B,N,K,P)
    const float* __restrict__ feats,  // (B,N,F)
    const float* __restrict__ mu,     // (N,K,D)
    const float* __restrict__ W1,     // (N,F,H)
    const float* __restrict__ Wx,     // (N,D,H)
    const float* __restrict__ b1,     // (N,H)
    const float* __restrict__ W2,     // (N,H)
    const float* __restrict__ bias2,  // (N,)
    const int* __restrict__ nbr,      // (N,2)
    float* __restrict__ wsPart,       // (1280,) tile sums
    float* __restrict__ out)          // (B,N,K,P) unnormalized
{
    __shared__ float4 sQ[Q_];            // neighbor point q: (x, y, z, c)
    __shared__ float4 aT[CR_];           // row: (4L*a0, 4L*a1, 4L*a2, -2L*|a|^2)
    __shared__ float4 xT[CR_];           // row: (x0, x1, x2, 0)
    __shared__ float4 gT[H_];            // h: (wx0, wx1, wx2, w2)
    __shared__ float  hbT[H_];           // h: hf + b1
    __shared__ float  gpart[H_][5];      // gemv f-segment partials (4 used)
    __shared__ float  tgate[CR_][5];     // gate h-segment partials (4 used)
    __shared__ float  part[CR_][17];     // row x slice partials (16 used)
    __shared__ float  red[4];
    __shared__ float  invW;              // 1/(sum W_neighbor + EPS)

    const int blk  = blockIdx.x;         // 0..1279
    const int bn   = blk >> 3;
    const int tile = blk & 7;
    const int b    = bn / N_;
    const int n    = bn - b * N_;
    const int tid  = threadIdx.x;        // 0..255
    const int wave = tid >> 6;
    const int lane = tid & 63;
    const int k    = (tile >= 4) ? 1 : 0;
    const int r0   = tile * CR_;         // row base in (k*320+p) flattening
    const int j    = nbr[n * 2 + k];     // component k pairs with neighbor k

    // ---- stage neighbor j's 640 points (vectorized: 4 points per thread) ----
    const size_t nbase = ((size_t)b * N_ + j) * Q_;
    float wsum = 0.f;
    if (tid < Q_ / 4) {                  // threads 0..159
        const int t = tid;
        const float4* xv = (const float4*)(X + nbase * D_);   // 16B-aligned
        const float4 f0 = xv[3 * t];
        const float4 f1 = xv[3 * t + 1];
        const float4 f2 = xv[3 * t + 2];
        const float4 w4 = ((const float4*)(W + nbase))[t];    // 16B-aligned
        const float c0 = w4.x * __builtin_amdgcn_exp2f(-2.f * LOG2E_ *
                         (f0.x * f0.x + f0.y * f0.y + f0.z * f0.z));
        const float c1 = w4.y * __builtin_amdgcn_exp2f(-2.f * LOG2E_ *
                         (f0.w * f0.w + f1.x * f1.x + f1.y * f1.y));
        const float c2 = w4.z * __builtin_amdgcn_exp2f(-2.f * LOG2E_ *
                         (f1.z * f1.z + f1.w * f1.w + f2.x * f2.x));
        const float c3 = w4.w * __builtin_amdgcn_exp2f(-2.f * LOG2E_ *
                         (f2.y * f2.y + f2.z * f2.z + f2.w * f2.w));
        sQ[4 * t]     = make_float4(f0.x, f0.y, f0.z, c0);
        sQ[4 * t + 1] = make_float4(f0.w, f1.x, f1.y, c1);
        sQ[4 * t + 2] = make_float4(f1.z, f1.w, f2.x, c2);
        sQ[4 * t + 3] = make_float4(f2.y, f2.z, f2.w, c3);
        wsum = (w4.x + w4.y) + (w4.z + w4.w);
    }
    {   // block-reduce neighbor weight sum (zeros from tid>=160)
        float v = wsum;
        #pragma unroll
        for (int off = 32; off > 0; off >>= 1) v += __shfl_down(v, off, 64);
        if (lane == 0) red[wave] = v;
    }

    // ---- hb gemv, parallel over 256 threads: h = tid&63, f-seg = tid>>6 ----
    {
        const int h = tid & 63, seg = tid >> 6;
        const float* fp  = feats + (size_t)bn * F_;
        const float* w1p = W1 + (size_t)n * F_ * H_ + h;
        float acc = 0.f;
        #pragma unroll
        for (int f = 0; f < 16; ++f) {
            const int ff = seg * 16 + f;
            acc = fmaf(fp[ff], w1p[(size_t)ff * H_], acc);
        }
        gpart[h][seg] = acc;
    }

    // ---- per-row params (threads 0..79) + gate tables (threads 0..63) ----
    if (tid < CR_) {
        const int gr = r0 + tid;         // flattened row of this (b,n)
        const float* xp = X + ((size_t)bn * Q_ + gr) * D_;
        const float x0 = xp[0], x1 = xp[1], x2 = xp[2];
        const float* mup = mu + (n * K_ + k) * D_;
        const float a0 = x0 - mup[0];
        const float a1 = x1 - mup[1];
        const float a2 = x2 - mup[2];
        const float ra2 = a0 * a0 + a1 * a1 + a2 * a2;
        aT[tid] = make_float4(a0 * (4.f * LOG2E_), a1 * (4.f * LOG2E_),
                              a2 * (4.f * LOG2E_), -2.f * LOG2E_ * ra2);
        xT[tid] = make_float4(x0, x1, x2, 0.f);
    }
    if (tid < H_) {
        const float* wxp = Wx + (size_t)n * D_ * H_ + tid;
        gT[tid] = make_float4(wxp[0], wxp[H_], wxp[2 * H_], W2[n * H_ + tid]);
    }
    __syncthreads();

    if (tid < H_)
        hbT[tid] = ((gpart[tid][0] + gpart[tid][1]) +
                    (gpart[tid][2] + gpart[tid][3])) + b1[n * H_ + tid];
    if (tid == 0)
        invW = 1.f / (((red[0] + red[1]) + (red[2] + red[3])) + EPS_);

    // ---- q-pass: thread = (row-group g: 5 rows, slice s: 40 strided q) ----
    const int g = tid >> 4;              // 0..15 (rows 5g..5g+4 of the tile)
    const int s = tid & 15;              // 0..15
    float S0[5], S1[5], S2[5], RA[5], acc[5];
    #pragma unroll
    for (int jj = 0; jj < 5; ++jj) {
        const float4 av = aT[g * 5 + jj];
        S0[jj] = av.x; S1[jj] = av.y; S2[jj] = av.z; RA[jj] = av.w;
        acc[jj] = 0.f;
    }
    #pragma unroll 4
    for (int i = 0; i < Q_ / 16; ++i) {  // 40 q per thread
        const float4 Pq = sQ[i * 16 + s];
        #pragma unroll
        for (int jj = 0; jj < 5; ++jj) {
            const float d = fmaf(Pq.x, S0[jj],
                            fmaf(Pq.y, S1[jj],
                            fmaf(Pq.z, S2[jj], RA[jj])));
            acc[jj] = fmaf(Pq.w, __builtin_amdgcn_exp2f(d), acc[jj]);
        }
    }
    #pragma unroll
    for (int jj = 0; jj < 5; ++jj)
        part[g * 5 + jj][s] = acc[jj];

    __syncthreads();

    // ---- gate phase A: rows 0..63 by all threads, rows 64..79 by tid<64 ----
    {
        const int row = tid & 63, seg = tid >> 6;
        const float4 xr = xT[row];
        float accg = 0.f;
        #pragma unroll
        for (int hh = 0; hh < 16; ++hh) {
            const int h = seg * 16 + hh;
            const float4 gv = gT[h];
            float t = fmaf(xr.x, gv.x, fmaf(xr.y, gv.y, fmaf(xr.z, gv.z, hbT[h])));
            t = fmaxf(t, 0.f);
            accg = fmaf(t, gv.w, accg);
        }
        tgate[row][seg] = accg;
    }
    if (tid < 64) {
        const int row = 64 + (tid & 15), seg = tid >> 4;
        const float4 xr = xT[row];
        float accg = 0.f;
        #pragma unroll
        for (int hh = 0; hh < 16; ++hh) {
            const int h = seg * 16 + hh;
            const float4 gv = gT[h];
            float t = fmaf(xr.x, gv.x, fmaf(xr.y, gv.y, fmaf(xr.z, gv.z, hbT[h])));
            t = fmaxf(t, 0.f);
            accg = fmaf(t, gv.w, accg);
        }
        tgate[row][seg] = accg;
    }
    __syncthreads();

    // ---- phase B: threads 0..79 combine, gate, store + tile partial ----
    float wval = 0.f;
    if (tid < CR_) {
        const int row = tid;
        const float* pr = part[row];
        const float msg =
            (((pr[0] + pr[1]) + (pr[2] + pr[3])) + ((pr[4] + pr[5]) + (pr[6] + pr[7]))) +
            (((pr[8] + pr[9]) + (pr[10] + pr[11])) + ((pr[12] + pr[13]) + (pr[14] + pr[15])));
        const float accg = bias2[n] + ((tgate[row][0] + tgate[row][1]) +
                                       (tgate[row][2] + tgate[row][3]));
        const float u = 1.f / (1.f + __expf(-accg));
        wval = u * msg * invW;           // invW: exact linear factor
        out[(size_t)bn * Q_ + r0 + row] = wval;
    }
    {   // block-reduce wval over threads 0..79 (others contribute 0)
        float v = wval;
        #pragma unroll
        for (int off = 32; off > 0; off >>= 1) v += __shfl_down(v, off, 64);
        if (lane == 0) red[wave] = v;
        __syncthreads();
        if (tid == 0)
            wsPart[blk] = (red[0] + red[1]) + (red[2] + red[3]);
    }
}

// ---------------- K2: normalize over (k,p) per (b,n) ----------------
__global__ __launch_bounds__(Q_) void norm_kernel(
    const float* __restrict__ wsPart, float* __restrict__ out)
{
    const int bn = blockIdx.x;
    const float* p = wsPart + bn * CT_;
    const float ssum = ((p[0] + p[1]) + (p[2] + p[3])) +
                       ((p[4] + p[5]) + (p[6] + p[7]));
    const float inv = 1.f / (ssum + EPS_);
    out[(size_t)bn * Q_ + threadIdx.x] *= inv;
}

extern "C" void kernel_launch(void* const* d_in, const int* in_sizes, int n_in,
                              void* d_out, int out_size, void* d_ws, size_t ws_size,
                              hipStream_t stream) {
    const float* X     = (const float*)d_in[0];
    const float* W     = (const float*)d_in[1];
    const float* feats = (const float*)d_in[2];
    const float* mu    = (const float*)d_in[3];
    const float* W1    = (const float*)d_in[4];
    const float* Wx    = (const float*)d_in[5];
    const float* b1    = (const float*)d_in[6];
    const float* W2    = (const float*)d_in[7];
    const float* bias2 = (const float*)d_in[8];
    const int*   nbr   = (const int*)d_in[9];
    float*       out   = (float*)d_out;
    float*       wsPart = (float*)d_ws;   // 1280 floats

    main_kernel<<<B_ * N_ * CT_, 256, 0, stream>>>(
        X, W, feats, mu, W1, Wx, b1, W2, bias2, nbr, wsPart, out);
    norm_kernel<<<B_ * N_, Q_, 0, stream>>>(wsPart, out);
}